// Round 4
// baseline (592.612 us; speedup 1.0000x reference)
//
#include <hip/hip_runtime.h>

// Splat conv (full true convolution):
//   out[oi, oj] = sum_{di,dj in [0,5)} in[oi-di, oj-dj] * f[di][dj]
// in:  8192 x 8192 fp32, out: 8196 x 8196 fp32 (no bias in forward).
//
// v4: persistent column-strip streaming. Each thread owns one float4 column
// group and walks SPAN=16 row-groups (64 output rows) with a rolling 8-row
// register window: only 4 new rows (8 float4) loaded per 16 outputs, and the
// next rows are prefetched BEFORE computing the current window so the wave
// streams loads continuously (copy-ubench style) instead of one-shot
// load->wait->compute->die.

#define IN_H 8192
#define IN_W 8192
#define OUT_H 8196
#define OUT_W 8196
#define NG 2049   // float4 groups per output row
#define NRG 2049  // output row-groups of 4 (2049*4 == 8196)
#define SPAN 16   // row-groups per thread (64 output rows)

__device__ __forceinline__ float sgpr_f32(float v) {
  return __int_as_float(__builtin_amdgcn_readfirstlane(__float_as_int(v)));
}

__global__ __launch_bounds__(256, 4) void splat_conv_kernel(
    const float* __restrict__ in, const float* __restrict__ flt,
    float* __restrict__ out) {
  const int g = blockIdx.x * 64 + threadIdx.x;  // col group (float4)
  if (g >= NG) return;
  const int strip = blockIdx.y * 4 + threadIdx.y;
  const int rg0 = strip * SPAN;
  if (rg0 >= NRG) return;
  const int rg1 = (rg0 + SPAN < NRG) ? rg0 + SPAN : NRG;

  // Filter: force into SGPRs (uniform across the wave).
  float f[25];
#pragma unroll
  for (int i = 0; i < 25; ++i) f[i] = sgpr_f32(flt[i]);

  const int c0 = 4 * g - 4;  // base input col (16B aligned)
  const bool col_int = (g >= 1) & (g <= NG - 2);
  // Fast path needs rows 4*rg0-4 .. 4*(rg1-1)+3 all inside [0, IN_H).
  const bool rows_ok = (rg0 >= 1) & (rg1 - 1 <= 2047);

  if (col_int & rows_ok) {
    // ---------- FAST streaming path ----------
    const float* rp = in + (size_t)(4 * rg0 - 4) * IN_W + c0;
    float4 W[8][2];  // rolling window: rows orow-4 .. orow+3
#pragma unroll
    for (int r = 0; r < 8; ++r) {
      W[r][0] = *(const float4*)(rp);
      W[r][1] = *(const float4*)(rp + 4);
      rp += IN_W;
    }
    float* op = out + (size_t)(4 * rg0) * OUT_W + 4 * g;

#pragma unroll 2
    for (int rg = rg0; rg < rg1 - 1; ++rg) {
      // Prefetch the 4 rows for the NEXT window (independent of W).
      float4 P[4][2];
#pragma unroll
      for (int r = 0; r < 4; ++r) {
        P[r][0] = *(const float4*)(rp);
        P[r][1] = *(const float4*)(rp + 4);
        rp += IN_W;
      }
      // Compute current 4 output rows from W.
      float acc[4][4];
#pragma unroll
      for (int k = 0; k < 4; ++k)
#pragma unroll
        for (int m = 0; m < 4; ++m) acc[k][m] = 0.f;
#pragma unroll
      for (int rr = 0; rr < 8; ++rr) {
        float x[8];
        x[0] = W[rr][0].x; x[1] = W[rr][0].y; x[2] = W[rr][0].z; x[3] = W[rr][0].w;
        x[4] = W[rr][1].x; x[5] = W[rr][1].y; x[6] = W[rr][1].z; x[7] = W[rr][1].w;
#pragma unroll
        for (int k = 0; k < 4; ++k) {
          const int di = k + 4 - rr;
          if (di < 0 || di > 4) continue;
#pragma unroll
          for (int dj = 0; dj < 5; ++dj) {
            const float w = f[di * 5 + dj];
#pragma unroll
            for (int m = 0; m < 4; ++m) acc[k][m] += x[m + 4 - dj] * w;
          }
        }
      }
      // Store 4 rows.
      float* o = op;
#pragma unroll
      for (int k = 0; k < 4; ++k) {
        *(float4*)(o) = make_float4(acc[k][0], acc[k][1], acc[k][2], acc[k][3]);
        o += OUT_W;
      }
      op += 4 * OUT_W;
      // Rotate window (static indices; unroll-2 lets compiler ping-pong).
#pragma unroll
      for (int r = 0; r < 4; ++r) {
        W[r][0] = W[r + 4][0]; W[r][1] = W[r + 4][1];
        W[r + 4][0] = P[r][0]; W[r + 4][1] = P[r][1];
      }
    }
    // Last row-group of the strip (no prefetch).
    {
      float acc[4][4];
#pragma unroll
      for (int k = 0; k < 4; ++k)
#pragma unroll
        for (int m = 0; m < 4; ++m) acc[k][m] = 0.f;
#pragma unroll
      for (int rr = 0; rr < 8; ++rr) {
        float x[8];
        x[0] = W[rr][0].x; x[1] = W[rr][0].y; x[2] = W[rr][0].z; x[3] = W[rr][0].w;
        x[4] = W[rr][1].x; x[5] = W[rr][1].y; x[6] = W[rr][1].z; x[7] = W[rr][1].w;
#pragma unroll
        for (int k = 0; k < 4; ++k) {
          const int di = k + 4 - rr;
          if (di < 0 || di > 4) continue;
#pragma unroll
          for (int dj = 0; dj < 5; ++dj) {
            const float w = f[di * 5 + dj];
#pragma unroll
            for (int m = 0; m < 4; ++m) acc[k][m] += x[m + 4 - dj] * w;
          }
        }
      }
      float* o = op;
#pragma unroll
      for (int k = 0; k < 4; ++k) {
        *(float4*)(o) = make_float4(acc[k][0], acc[k][1], acc[k][2], acc[k][3]);
        o += OUT_W;
      }
    }
  } else {
    // ---------- SLOW guarded path (image edges; <2% of work) ----------
    const bool lo_ok = (g != 0);
    const bool hi_ok = (g != NG - 1);
    for (int rg = rg0; rg < rg1; ++rg) {
      const int orow = rg * 4;
      float4 A[8], B[8];
#pragma unroll
      for (int rr = 0; rr < 8; ++rr) {
        const int r = orow - 4 + rr;
        A[rr] = make_float4(0.f, 0.f, 0.f, 0.f);
        B[rr] = make_float4(0.f, 0.f, 0.f, 0.f);
        if (r >= 0 && r < IN_H) {
          const float* rp = in + (size_t)r * IN_W + c0;
          if (lo_ok) A[rr] = *(const float4*)(rp);
          if (hi_ok) B[rr] = *(const float4*)(rp + 4);
        }
      }
      float acc[4][4];
#pragma unroll
      for (int k = 0; k < 4; ++k)
#pragma unroll
        for (int m = 0; m < 4; ++m) acc[k][m] = 0.f;
#pragma unroll
      for (int rr = 0; rr < 8; ++rr) {
        float x[8];
        x[0] = A[rr].x; x[1] = A[rr].y; x[2] = A[rr].z; x[3] = A[rr].w;
        x[4] = B[rr].x; x[5] = B[rr].y; x[6] = B[rr].z; x[7] = B[rr].w;
#pragma unroll
        for (int k = 0; k < 4; ++k) {
          const int di = k + 4 - rr;
          if (di < 0 || di > 4) continue;
#pragma unroll
          for (int dj = 0; dj < 5; ++dj) {
            const float w = f[di * 5 + dj];
#pragma unroll
            for (int m = 0; m < 4; ++m) acc[k][m] += x[m + 4 - dj] * w;
          }
        }
      }
      float* o = out + (size_t)orow * OUT_W + 4 * g;
#pragma unroll
      for (int k = 0; k < 4; ++k) {
        *(float4*)(o) = make_float4(acc[k][0], acc[k][1], acc[k][2], acc[k][3]);
        o += OUT_W;
      }
    }
  }
}

extern "C" void kernel_launch(void* const* d_in, const int* in_sizes, int n_in,
                              void* d_out, int out_size, void* d_ws,
                              size_t ws_size, hipStream_t stream) {
  const float* in = (const float*)d_in[0];
  const float* flt = (const float*)d_in[1];
  // d_in[2] = bias: NOT used by the forward reference.
  float* out = (float*)d_out;

  const int nstrips = (NRG + SPAN - 1) / SPAN;       // 129
  dim3 block(64, 4);                                 // 256 threads
  dim3 grid((NG + 63) / 64, (nstrips + 3) / 4);      // 33 x 33
  splat_conv_kernel<<<grid, block, 0, stream>>>(in, flt, out);
}